// Round 5
// baseline (522.070 us; speedup 1.0000x reference)
//
#include <hip/hip_runtime.h>
#include <stdint.h>
#include <math.h>

// Problem constants (fixed by the reference setup_inputs).
#define PP 131072   // priors
#define BB 32       // batch
#define AA 32       // truths per image
#define THRESH 0.35f

// ws layout (bytes) — footprint identical to the passing round-1/4 runs:
//   0    : double accL[32]
//   256  : double accC[32]
//   512  : double accLM[32]
//   768  : int    numpos[32]
//   1024 : u32    ovr[BB*AA]   (per-truth best prior index)     4 KiB
//   9216 : u32    sel[BB][4]   (prefix, krem)                   512 B
//   16384: u8     bti[BB*PP]                                    4 MiB
//          ^-- u32 hist[BB][2048] ALIASES bti (bti dead after k_loss)
//   OFF_LM : float loss_mine[BB*PP]                             16 MiB
static constexpr size_t OFF_ACCL = 0;
static constexpr size_t OFF_ACCC = 256;
static constexpr size_t OFF_ACCLM = 512;
static constexpr size_t OFF_NP = 768;
static constexpr size_t OFF_OVR = 1024;
static constexpr size_t OFF_SEL = 9216;
static constexpr size_t OFF_BTI = 16384;
static constexpr size_t OFF_HIST = OFF_BTI;  // alias, see above
static constexpr size_t OFF_LM = 16384 + (size_t)BB * PP;

// ---------------------------------------------------------------------------
// K1a: per-prior best truth ONLY (cross-mult compares, no divides in the
// loop, no cross-lane ops, no atomics). Grid (PP/2048, BB) x 256; each
// thread owns 8 priors in registers and loops 32 truths.
// ---------------------------------------------------------------------------
__global__ __launch_bounds__(256) void k_prior(
    const float* __restrict__ priors, const float* __restrict__ targets,
    unsigned char* __restrict__ bti) {
#pragma clang fp contract(off)
  const int b = blockIdx.y;
  const int tid = threadIdx.x;
  __shared__ float tx0[AA], ty0[AA], tx1[AA], ty1[AA], tar[AA];
  if (tid < AA) {
    const float* tg = targets + ((size_t)b * AA + tid) * 15;
    float a0 = tg[0], a1 = tg[1], a2 = tg[2], a3 = tg[3];
    tx0[tid] = a0; ty0[tid] = a1; tx1[tid] = a2; ty1[tid] = a3;
    tar[tid] = (a2 - a0) * (a3 - a1);
  }
  __syncthreads();

  const int base = blockIdx.x * 2048;
  float px0[8], py0[8], px1[8], py1[8], areaB[8];
  float cbi[8], cbd[8];
  int cba[8];
#pragma unroll
  for (int i = 0; i < 8; ++i) {
    const int p = base + i * 256 + tid;
    const float4 pr = reinterpret_cast<const float4*>(priors)[p];
    const float hx = pr.z * 0.5f, hy = pr.w * 0.5f;
    px0[i] = pr.x - hx; py0[i] = pr.y - hy;
    px1[i] = pr.x + hx; py1[i] = pr.y + hy;
    areaB[i] = (px1[i] - px0[i]) * (py1[i] - py0[i]);
    cbi[i] = -1.f; cbd[i] = 1.f; cba[i] = 0;
  }

  for (int a = 0; a < AA; ++a) {
    const float sx0 = tx0[a], sy0 = ty0[a], sx1 = tx1[a], sy1 = ty1[a];
    const float sar = tar[a];
#pragma unroll
    for (int i = 0; i < 8; ++i) {
      const float wx = fmaxf(fminf(sx1, px1[i]) - fmaxf(sx0, px0[i]), 0.f);
      const float wy = fmaxf(fminf(sy1, py1[i]) - fmaxf(sy0, py0[i]), 0.f);
      const float inter = wx * wy;
      const float den = sar + areaB[i] - inter;
      // strict >, a ascending => first occurrence wins (jnp.argmax)
      if (inter * cbd[i] > cbi[i] * den) { cbi[i] = inter; cbd[i] = den; cba[i] = a; }
    }
  }

#pragma unroll
  for (int i = 0; i < 8; ++i) {
    const int p = base + i * 256 + tid;
    const float r = cbi[i] / cbd[i];   // rounded, matches reference < THRESH
    bti[(size_t)b * PP + p] =
        (unsigned char)cba[i] | ((r < THRESH) ? 0 : 32);
  }
}

// ---------------------------------------------------------------------------
// K1b: per-truth best prior. One block per (batch, truth-pair); each thread
// chains 512 priors with div-free cross-mult compares; one division + one
// u64 butterfly + LDS combine per block. Direct store, no atomics.
// ---------------------------------------------------------------------------
__global__ __launch_bounds__(256) void k_truth(
    const float* __restrict__ priors, const float* __restrict__ targets,
    unsigned* __restrict__ ovr) {
#pragma clang fp contract(off)
  const int b = blockIdx.y;
  const int a0 = blockIdx.x * 2;
  const int tid = threadIdx.x;
  const float* tg0 = targets + ((size_t)b * AA + a0) * 15;
  const float s0x0 = tg0[0], s0y0 = tg0[1], s0x1 = tg0[2], s0y1 = tg0[3];
  const float s1x0 = tg0[15], s1y0 = tg0[16], s1x1 = tg0[17], s1y1 = tg0[18];
  const float sar0 = (s0x1 - s0x0) * (s0y1 - s0y0);
  const float sar1 = (s1x1 - s1x0) * (s1y1 - s1y0);
  float bi0 = -1.f, bd0 = 1.f, bi1 = -1.f, bd1 = 1.f;
  int bp0 = 0, bp1 = 0;
  const float4* __restrict__ pr4 = reinterpret_cast<const float4*>(priors);
#pragma unroll 4
  for (int k = 0; k < PP / 256; ++k) {
    const int p = k * 256 + tid;
    const float4 pr = pr4[p];
    const float hx = pr.z * 0.5f, hy = pr.w * 0.5f;
    const float px0 = pr.x - hx, py0 = pr.y - hy;
    const float px1 = pr.x + hx, py1 = pr.y + hy;
    const float areaB = (px1 - px0) * (py1 - py0);
    {
      const float wx = fmaxf(fminf(s0x1, px1) - fmaxf(s0x0, px0), 0.f);
      const float wy = fmaxf(fminf(s0y1, py1) - fmaxf(s0y0, py0), 0.f);
      const float inter = wx * wy;
      const float den = sar0 + areaB - inter;
      if (inter * bd0 > bi0 * den) { bi0 = inter; bd0 = den; bp0 = p; }
    }
    {
      const float wx = fmaxf(fminf(s1x1, px1) - fmaxf(s1x0, px0), 0.f);
      const float wy = fmaxf(fminf(s1y1, py1) - fmaxf(s1y0, py0), 0.f);
      const float inter = wx * wy;
      const float den = sar1 + areaB - inter;
      if (inter * bd1 > bi1 * den) { bi1 = inter; bd1 = den; bp1 = p; }
    }
  }
  // one rounded division per truth (argmax on rounded r, min index on ties)
  const float r0 = bi0 / bd0, r1 = bi1 / bd1;
  unsigned long long k0 =
      ((unsigned long long)__float_as_uint(r0) << 32) |
      (unsigned long long)(0xFFFFFFFFu - (unsigned)bp0);
  unsigned long long k1 =
      ((unsigned long long)__float_as_uint(r1) << 32) |
      (unsigned long long)(0xFFFFFFFFu - (unsigned)bp1);
#pragma unroll
  for (int off = 1; off < 64; off <<= 1) {
    unsigned long long o0 = __shfl_xor(k0, off, 64);
    if (o0 > k0) k0 = o0;
    unsigned long long o1 = __shfl_xor(k1, off, 64);
    if (o1 > k1) k1 = o1;
  }
  __shared__ unsigned long long red[4][2];
  const int wv = tid >> 6, lane = tid & 63;
  if (lane == 0) { red[wv][0] = k0; red[wv][1] = k1; }
  __syncthreads();
  if (tid < 2) {
    unsigned long long m = red[0][tid];
#pragma unroll
    for (int w = 1; w < 4; ++w)
      if (red[w][tid] > m) m = red[w][tid];
    ovr[b * AA + a0 + tid] = 0xFFFFFFFFu - (unsigned)(m & 0xFFFFFFFFull);
  }
}

// ---------------------------------------------------------------------------
// K1c: apply the per-truth override into bti. One thread per batch, a
// ascending sequentially => duplicate priors resolve last-truth-wins,
// exactly matching the reference's .at[best_prior_idx].set scatter.
// ---------------------------------------------------------------------------
__global__ void k_override(const unsigned* __restrict__ ovr,
                           unsigned char* __restrict__ bti) {
  const int b = threadIdx.x;
  if (b < BB) {
    for (int a = 0; a < AA; ++a) {
      const unsigned p = ovr[b * AA + a];
      bti[(size_t)b * PP + p] = (unsigned char)(a | 32);
    }
  }
}

// ---------------------------------------------------------------------------
// K2: conf loss for all priors (writes loss_mine), sparse loc / landmark
// losses for positives. Per-batch double accumulators. Reads bti only.
// ---------------------------------------------------------------------------
__global__ __launch_bounds__(256) void k_loss(
    const float* __restrict__ loc, const float* __restrict__ conf,
    const float* __restrict__ loc5, const float* __restrict__ priors,
    const float* __restrict__ targets,
    const unsigned char* __restrict__ bti, float* __restrict__ lossm,
    double* __restrict__ accL, double* __restrict__ accC,
    double* __restrict__ accLM, int* __restrict__ numpos) {
#pragma clang fp contract(off)
  const int b = blockIdx.y;
  const int tid = threadIdx.x;
  __shared__ float tr[AA][15];
  if (tid < AA) {
    const float* tg = targets + ((size_t)b * AA + tid) * 15;
#pragma unroll
    for (int j = 0; j < 15; ++j) tr[tid][j] = tg[j];
  }
  __syncthreads();

  double ll = 0.0, lc = 0.0, lm = 0.0;
  int np = 0;
  const int base = blockIdx.x * 2048;
  for (int it = 0; it < 8; ++it) {
    const int p = base + it * 256 + tid;
    const size_t gp = (size_t)b * PP + p;
    const unsigned char f = bti[gp];
    const int idx = f & 31;
    const bool posf = (f & 32) != 0;
    const int cls = posf ? (int)tr[idx][4] : 0;
    const bool pos = cls > 0;

    const float2 cc = reinterpret_cast<const float2*>(conf)[gp];
    const float mx = fmaxf(cc.x, cc.y);
    const float lse = mx + logf(expf(cc.x - mx) + expf(cc.y - mx));
    const float gtl = (cls >= 1) ? cc.y : cc.x;
    const float lca = lse - gtl;
    lossm[gp] = pos ? 0.f : lca;

    if (pos) {
      ++np;
      lc += (double)lca;
      const float4 pr = reinterpret_cast<const float4*>(priors)[p];
      const float m0 = tr[idx][0], m1 = tr[idx][1];
      const float m2 = tr[idx][2], m3 = tr[idx][3];
      const float vx = 0.1f * pr.z, vy = 0.1f * pr.w;
      const float t0 = ((m0 + m2) / 2.0f - pr.x) / vx;
      const float t1 = ((m1 + m3) / 2.0f - pr.y) / vy;
      const float t2 = logf((m2 - m0) / pr.z) / 0.2f;
      const float t3 = logf((m3 - m1) / pr.w) / 0.2f;
      const float* lp = loc + gp * 4;
      float s = 0.f;
      {
        float d = lp[0] - t0, ad = fabsf(d);
        s += (ad < 1.f) ? 0.5f * d * d : ad - 0.5f;
        d = lp[1] - t1; ad = fabsf(d);
        s += (ad < 1.f) ? 0.5f * d * d : ad - 0.5f;
        d = lp[2] - t2; ad = fabsf(d);
        s += (ad < 1.f) ? 0.5f * d * d : ad - 0.5f;
        d = lp[3] - t3; ad = fabsf(d);
        s += (ad < 1.f) ? 0.5f * d * d : ad - 0.5f;
      }
      ll += (double)s;
      const float* l5 = loc5 + gp * 10;
      float s2 = 0.f;
#pragma unroll
      for (int j = 0; j < 5; ++j) {
        const float tx = (tr[idx][5 + 2 * j] - pr.x) / vx;
        const float ty = (tr[idx][6 + 2 * j] - pr.y) / vy;
        const float dx = l5[2 * j] - tx;
        const float dy = l5[2 * j + 1] - ty;
        s2 += dx * dx + dy * dy;
      }
      lm += (double)s2;
    }
  }
#pragma unroll
  for (int off = 1; off < 64; off <<= 1) {
    ll += __shfl_xor(ll, off, 64);
    lc += __shfl_xor(lc, off, 64);
    lm += __shfl_xor(lm, off, 64);
    np += __shfl_xor(np, off, 64);
  }
  __shared__ double rl[4], rc[4], rm[4];
  __shared__ int rn[4];
  const int wave = tid >> 6, lane = tid & 63;
  if (lane == 0) { rl[wave] = ll; rc[wave] = lc; rm[wave] = lm; rn[wave] = np; }
  __syncthreads();
  if (tid == 0) {
    atomicAdd(&accL[b], rl[0] + rl[1] + rl[2] + rl[3]);
    atomicAdd(&accC[b], rc[0] + rc[1] + rc[2] + rc[3]);
    atomicAdd(&accLM[b], rm[0] + rm[1] + rm[2] + rm[3]);
    atomicAdd(&numpos[b], rn[0] + rn[1] + rn[2] + rn[3]);
  }
}

// ---------------------------------------------------------------------------
// Radix-select pass: per-batch histogram of BITS bits at SHIFT, over elements
// whose higher bits match sel[b].prefix. Grid (8, BB) x 256; LDS-privatized
// histograms, sparse flush to global per-batch histogram.
// ---------------------------------------------------------------------------
template <int SHIFT, int BITS>
__global__ __launch_bounds__(256) void k_hist(
    const float* __restrict__ lossm, const unsigned* __restrict__ sel,
    unsigned* __restrict__ hist) {
  const int b = blockIdx.y;
  const int tid = threadIdx.x;
  constexpr int NBINS = 1 << BITS;
  __shared__ unsigned h[NBINS];
  for (int i = tid; i < NBINS; i += 256) h[i] = 0;
  __syncthreads();
  const unsigned hmask =
      (SHIFT + BITS >= 32) ? 0u : (0xFFFFFFFFu << (SHIFT + BITS));
  const unsigned pref = (SHIFT + BITS >= 32) ? 0u : (sel[b * 4] & hmask);
  const float4* v4 = reinterpret_cast<const float4*>(lossm + (size_t)b * PP) +
                     (size_t)blockIdx.x * 4096;
#pragma unroll 4
  for (int k = 0; k < 16; ++k) {
    const float4 x = v4[tid + k * 256];
    const unsigned u0 = __float_as_uint(x.x), u1 = __float_as_uint(x.y);
    const unsigned u2 = __float_as_uint(x.z), u3 = __float_as_uint(x.w);
    if ((u0 & hmask) == pref) atomicAdd(&h[(u0 >> SHIFT) & (NBINS - 1)], 1u);
    if ((u1 & hmask) == pref) atomicAdd(&h[(u1 >> SHIFT) & (NBINS - 1)], 1u);
    if ((u2 & hmask) == pref) atomicAdd(&h[(u2 >> SHIFT) & (NBINS - 1)], 1u);
    if ((u3 & hmask) == pref) atomicAdd(&h[(u3 >> SHIFT) & (NBINS - 1)], 1u);
  }
  __syncthreads();
  unsigned* H = hist + b * 2048;
  for (int i = tid; i < NBINS; i += 256) {
    const unsigned c = h[i];
    if (c) atomicAdd(&H[i], c);
  }
}

// ---------------------------------------------------------------------------
// Select the bin containing the krem-th largest value; update prefix/krem;
// zero the histogram for the next pass. 32 blocks (one per batch).
// ---------------------------------------------------------------------------
template <int SHIFT, int BITS, bool FIRST>
__global__ __launch_bounds__(256) void k_select(
    unsigned* __restrict__ hist, unsigned* __restrict__ sel,
    const int* __restrict__ numpos) {
  const int b = blockIdx.x;
  const int tid = threadIdx.x;
  constexpr int NBINS = 1 << BITS;
  constexpr int CH = NBINS / 256;
  unsigned* H = hist + b * 2048;
  __shared__ unsigned hb[2048];
  __shared__ unsigned csum[256];
  __shared__ unsigned s_krem;
  if (tid == 0) {
    if (FIRST) {
      long long K = 7LL * (long long)numpos[b];
      if (K > PP - 1) K = PP - 1;
      if (K <= 0) {
        s_krem = 0;
        sel[b * 4] = 0xFFFFFFFFu;  // sentinel: selects nothing
        sel[b * 4 + 1] = 0;
      } else {
        s_krem = (unsigned)K;
      }
    } else {
      s_krem = sel[b * 4 + 1];
    }
  }
  for (int i = tid; i < NBINS; i += 256) hb[i] = H[i];
  __syncthreads();
  const int start = NBINS - 1 - tid * CH;
  unsigned msum = 0;
#pragma unroll
  for (int j = 0; j < CH; ++j) msum += hb[start - j];
  csum[tid] = msum;
  for (int i = tid; i < 2048; i += 256) H[i] = 0;
  __syncthreads();
  if (tid == 0) {
    unsigned krem = s_krem;
    if (krem > 0) {
      unsigned cum = 0;
      int c = 0;
      while (c < 255 && cum + csum[c] < krem) { cum += csum[c]; ++c; }
      const int st = NBINS - 1 - c * CH;
      int bin = st - (CH - 1);
      for (int j = 0; j < CH; ++j) {
        const unsigned hh = hb[st - j];
        if (cum + hh >= krem) { bin = st - j; break; }
        cum += hh;
      }
      unsigned pref = FIRST ? 0u : sel[b * 4];
      pref |= ((unsigned)bin) << SHIFT;
      sel[b * 4] = pref;
      sel[b * 4 + 1] = krem - cum;  // ties at threshold to include
    }
  }
}

// ---------------------------------------------------------------------------
// Sum values strictly above the exact threshold. Grid (8, BB) x 256.
// ---------------------------------------------------------------------------
__global__ __launch_bounds__(256) void k_sumtop(
    const float* __restrict__ lossm, const unsigned* __restrict__ sel,
    double* __restrict__ accC) {
  const int b = blockIdx.y;
  const int tid = threadIdx.x;
  const unsigned pref = sel[b * 4];
  const float4* v4 = reinterpret_cast<const float4*>(lossm + (size_t)b * PP) +
                     (size_t)blockIdx.x * 4096;
  double s = 0.0;
#pragma unroll 4
  for (int k = 0; k < 16; ++k) {
    const float4 x = v4[tid + k * 256];
    if (__float_as_uint(x.x) > pref) s += (double)x.x;
    if (__float_as_uint(x.y) > pref) s += (double)x.y;
    if (__float_as_uint(x.z) > pref) s += (double)x.z;
    if (__float_as_uint(x.w) > pref) s += (double)x.w;
  }
#pragma unroll
  for (int off = 1; off < 64; off <<= 1) s += __shfl_xor(s, off, 64);
  __shared__ double rs[4];
  const int wave = tid >> 6, lane = tid & 63;
  if (lane == 0) rs[wave] = s;
  __syncthreads();
  if (tid == 0) atomicAdd(&accC[b], rs[0] + rs[1] + rs[2] + rs[3]);
}

// ---------------------------------------------------------------------------
// K4: finalize -> d_out[3] = {loss_l/N, loss_c/N, loss_coords/N}
// Adds the krem*thr tie contribution per batch.
// ---------------------------------------------------------------------------
__global__ void k_final(const double* __restrict__ accL,
                        const double* __restrict__ accC,
                        const double* __restrict__ accLM,
                        const int* __restrict__ numpos,
                        const unsigned* __restrict__ sel,
                        float* __restrict__ out) {
  if (threadIdx.x == 0 && blockIdx.x == 0) {
    long long tot = 0;
    double sl = 0, sc = 0, sm = 0;
    for (int b = 0; b < BB; ++b) {
      tot += numpos[b];
      sl += accL[b];
      sc += accC[b];
      const unsigned krem = sel[b * 4 + 1];
      if (krem > 0)
        sc += (double)krem * (double)__uint_as_float(sel[b * 4]);
      sm += accLM[b];
    }
    float N = (float)tot;
    if (N < 1.f) N = 1.f;
    out[0] = (float)(sl / (double)N);
    out[1] = (float)(sc / (double)N);
    out[2] = (float)(sm / (double)N);
  }
}

extern "C" void kernel_launch(void* const* d_in, const int* in_sizes, int n_in,
                              void* d_out, int out_size, void* d_ws,
                              size_t ws_size, hipStream_t stream) {
  const float* loc = (const float*)d_in[0];
  const float* conf = (const float*)d_in[1];
  const float* loc5 = (const float*)d_in[2];
  const float* priors = (const float*)d_in[3];
  const float* tgt = (const float*)d_in[4];
  char* ws = (char*)d_ws;
  double* accL = (double*)(ws + OFF_ACCL);
  double* accC = (double*)(ws + OFF_ACCC);
  double* accLM = (double*)(ws + OFF_ACCLM);
  int* numpos = (int*)(ws + OFF_NP);
  unsigned* ovr = (unsigned*)(ws + OFF_OVR);
  unsigned char* bti = (unsigned char*)(ws + OFF_BTI);
  float* lossm = (float*)(ws + OFF_LM);
  unsigned* hist = (unsigned*)(ws + OFF_HIST);  // aliases bti (dead by then)
  unsigned* sel = (unsigned*)(ws + OFF_SEL);

  // zero accumulators + numpos (first 1 KiB); ovr fully overwritten by k_truth
  hipMemsetAsync(d_ws, 0, 1024, stream);

  dim3 grid(PP / 2048, BB);
  k_prior<<<grid, 256, 0, stream>>>(priors, tgt, bti);
  k_truth<<<dim3(AA / 2, BB), 256, 0, stream>>>(priors, tgt, ovr);
  k_override<<<1, 64, 0, stream>>>(ovr, bti);
  k_loss<<<grid, 256, 0, stream>>>(loc, conf, loc5, priors, tgt, bti,
                                   lossm, accL, accC, accLM, numpos);
  // bti is dead from here; reuse its storage for the radix histograms
  hipMemsetAsync(ws + OFF_HIST, 0, (size_t)BB * 2048 * 4, stream);
  dim3 hgrid(8, BB);
  k_hist<21, 11><<<hgrid, 256, 0, stream>>>(lossm, sel, hist);
  k_select<21, 11, true><<<BB, 256, 0, stream>>>(hist, sel, numpos);
  k_hist<10, 11><<<hgrid, 256, 0, stream>>>(lossm, sel, hist);
  k_select<10, 11, false><<<BB, 256, 0, stream>>>(hist, sel, numpos);
  k_hist<0, 10><<<hgrid, 256, 0, stream>>>(lossm, sel, hist);
  k_select<0, 10, false><<<BB, 256, 0, stream>>>(hist, sel, numpos);
  k_sumtop<<<hgrid, 256, 0, stream>>>(lossm, sel, accC);
  k_final<<<1, 64, 0, stream>>>(accL, accC, accLM, numpos, sel,
                                (float*)d_out);
}

// Round 8
// 445.676 us; speedup vs baseline: 1.1714x; 1.1714x over previous
//
#include <hip/hip_runtime.h>
#include <stdint.h>
#include <math.h>

// Problem constants (fixed by the reference setup_inputs).
#define PP 131072   // priors
#define BB 32       // batch
#define AA 32       // truths per image
#define THRESH 0.35f

// ws layout (bytes). ws_size is ~640 MiB (measured via harness poison fill),
// so no aliasing games needed.
//   0    : double accL[32] / 256: accC / 512: accLM / 768: int numpos[32]
//   1024 : u32 sel1[BB][2]  (bin, krem after pass 1)
//   1280 : u32 sel2[BB][2]
//   1536 : u32 sel3[BB][2]  (final threshold bits, krem)
//   4096 : u64 gpart[BB][AA][64]   per-(batch,truth,block) argmax partials
//   1 MiB: u32 H1[BB][2048]; +256K: H2; +512K: H3   (zeroed once upfront)
//   2 MiB: u8  bti[BB*PP]   (best-truth idx | pos<<5)          4 MiB
//   8 MiB: f32 lossm[BB*PP]                                    16 MiB
static constexpr size_t OFF_ACCL = 0;
static constexpr size_t OFF_ACCC = 256;
static constexpr size_t OFF_ACCLM = 512;
static constexpr size_t OFF_NP = 768;
static constexpr size_t OFF_SEL1 = 1024;
static constexpr size_t OFF_SEL2 = 1280;
static constexpr size_t OFF_SEL3 = 1536;
static constexpr size_t OFF_GPART = 4096;
static constexpr size_t OFF_H1 = (size_t)1 << 20;
static constexpr size_t OFF_H2 = OFF_H1 + (size_t)BB * 2048 * 4;
static constexpr size_t OFF_H3 = OFF_H2 + (size_t)BB * 2048 * 4;
static constexpr size_t OFF_BTI = (size_t)2 << 20;
static constexpr size_t OFF_LM = (size_t)8 << 20;

// ---------------------------------------------------------------------------
// K1: ONE IoU pass computing BOTH argmaxes.
// Per-prior best truth -> bti (idx | flag). Per-truth best prior: 4-lane
// shfl reduce (cross-mult, no div) -> LDS [truth][64] -> 2-stage LDS tree ->
// one division per (block,truth) -> u64 key partial to gpart.
// Grid (PP/2048, BB) x 256; each thread owns 8 priors in registers.
// ---------------------------------------------------------------------------
__global__ __launch_bounds__(256) void k_match2(
    const float* __restrict__ priors, const float* __restrict__ targets,
    unsigned char* __restrict__ bti, unsigned long long* __restrict__ gpart) {
#pragma clang fp contract(off)
  const int b = blockIdx.y;
  const int tid = threadIdx.x;
  __shared__ float tx0[AA], ty0[AA], tx1[AA], ty1[AA], tar[AA];
  __shared__ float rbi[AA][65], rbd[AA][65];  // pad 65: bank-conflict-free
  __shared__ int rbp[AA][65];
  __shared__ float r2bi[AA][9], r2bd[AA][9];
  __shared__ int r2bp[AA][9];
  if (tid < AA) {
    const float* tg = targets + ((size_t)b * AA + tid) * 15;
    float a0 = tg[0], a1 = tg[1], a2 = tg[2], a3 = tg[3];
    tx0[tid] = a0; ty0[tid] = a1; tx1[tid] = a2; ty1[tid] = a3;
    tar[tid] = (a2 - a0) * (a3 - a1);
  }
  __syncthreads();

  const int base = blockIdx.x * 2048;
  float px0[8], py0[8], px1[8], py1[8], areaB[8];
  float cbi[8], cbd[8];
  int cba[8];
#pragma unroll
  for (int i = 0; i < 8; ++i) {
    const int p = base + i * 256 + tid;
    const float4 pr = reinterpret_cast<const float4*>(priors)[p];
    const float hx = pr.z * 0.5f, hy = pr.w * 0.5f;
    px0[i] = pr.x - hx; py0[i] = pr.y - hy;
    px1[i] = pr.x + hx; py1[i] = pr.y + hy;
    areaB[i] = (px1[i] - px0[i]) * (py1[i] - py0[i]);
    cbi[i] = -1.f; cbd[i] = 1.f; cba[i] = 0;
  }

  for (int a = 0; a < AA; ++a) {
    const float sx0 = tx0[a], sy0 = ty0[a], sx1 = tx1[a], sy1 = ty1[a];
    const float sar = tar[a];
    float bi = -1.f, bd = 1.f;  // this truth's best over my 8 priors
    int bp = 0;
#pragma unroll
    for (int i = 0; i < 8; ++i) {
      const float wx = fmaxf(fminf(sx1, px1[i]) - fmaxf(sx0, px0[i]), 0.f);
      const float wy = fmaxf(fminf(sy1, py1[i]) - fmaxf(sy0, py0[i]), 0.f);
      const float inter = wx * wy;
      const float den = sar + areaB[i] - inter;
      // per-prior best over truths (strict >, a ascending => first occurrence)
      if (inter * cbd[i] > cbi[i] * den) { cbi[i] = inter; cbd[i] = den; cba[i] = a; }
      // per-truth best over priors (strict >, p ascending within thread)
      if (inter * bd > bi * den) { bi = inter; bd = den; bp = base + i * 256 + tid; }
    }
    // 4-lane group reduce (xor 1, xor 2), tie on equal products -> min index
#pragma unroll
    for (int off = 1; off <= 2; off <<= 1) {
      const float obi = __shfl_xor(bi, off, 64);
      const float obd = __shfl_xor(bd, off, 64);
      const int obp = __shfl_xor(bp, off, 64);
      const float l = obi * bd, r = bi * obd;
      const bool take = (l > r) || (l == r && obp < bp);
      bi = take ? obi : bi; bd = take ? obd : bd; bp = take ? obp : bp;
    }
    if ((tid & 3) == 0) {
      rbi[a][tid >> 2] = bi; rbd[a][tid >> 2] = bd; rbp[a][tid >> 2] = bp;
    }
  }

  // per-prior threshold + bti write
#pragma unroll
  for (int i = 0; i < 8; ++i) {
    const int p = base + i * 256 + tid;
    const float r = cbi[i] / cbd[i];  // rounded, matches reference < THRESH
    bti[(size_t)b * PP + p] = (unsigned char)cba[i] | ((r < THRESH) ? 0 : 32);
  }

  __syncthreads();
  // stage 2: 32 truths x 8 chunks of 8 slots
  {
    const int a = tid & 31, c = tid >> 5;
    float bi = rbi[a][c * 8], bd = rbd[a][c * 8];
    int bp = rbp[a][c * 8];
#pragma unroll
    for (int j = 1; j < 8; ++j) {
      const float obi = rbi[a][c * 8 + j], obd = rbd[a][c * 8 + j];
      const int obp = rbp[a][c * 8 + j];
      const float l = obi * bd, r = bi * obd;
      const bool take = (l > r) || (l == r && obp < bp);
      bi = take ? obi : bi; bd = take ? obd : bd; bp = take ? obp : bp;
    }
    r2bi[a][c] = bi; r2bd[a][c] = bd; r2bp[a][c] = bp;
  }
  __syncthreads();
  // stage 3: one thread per truth; single division; u64 key partial
  if (tid < AA) {
    float bi = r2bi[tid][0], bd = r2bd[tid][0];
    int bp = r2bp[tid][0];
#pragma unroll
    for (int j = 1; j < 8; ++j) {
      const float obi = r2bi[tid][j], obd = r2bd[tid][j];
      const int obp = r2bp[tid][j];
      const float l = obi * bd, r = bi * obd;
      const bool take = (l > r) || (l == r && obp < bp);
      bi = take ? obi : bi; bd = take ? obd : bd; bp = take ? obp : bp;
    }
    const float r = bi / bd;
    const unsigned long long key =
        ((unsigned long long)__float_as_uint(r) << 32) |
        (unsigned long long)(0xFFFFFFFFu - (unsigned)bp);
    gpart[((size_t)b * AA + tid) * 64 + blockIdx.x] = key;
  }
}

// ---------------------------------------------------------------------------
// K1b: reduce the 64 per-block partials per (batch,truth), apply override
// into bti (a ascending by one thread => last-truth-wins, matching the
// reference scatter). One block per batch.
// ---------------------------------------------------------------------------
__global__ __launch_bounds__(256) void k_truthapply(
    const unsigned long long* __restrict__ gpart,
    unsigned char* __restrict__ bti) {
  const int b = blockIdx.x;
  const int tid = threadIdx.x;
  __shared__ unsigned long long p2[AA][9];
  __shared__ unsigned ovp[AA];
  {
    const int a = tid >> 3, j = tid & 7;
    const unsigned long long* g = gpart + ((size_t)b * AA + a) * 64 + j * 8;
    unsigned long long m = g[0];
#pragma unroll
    for (int k = 1; k < 8; ++k) if (g[k] > m) m = g[k];
    p2[a][j] = m;
  }
  __syncthreads();
  if (tid < AA) {
    unsigned long long m = p2[tid][0];
#pragma unroll
    for (int k = 1; k < 8; ++k) if (p2[tid][k] > m) m = p2[tid][k];
    ovp[tid] = 0xFFFFFFFFu - (unsigned)(m & 0xFFFFFFFFull);
  }
  __syncthreads();
  if (tid == 0) {
    for (int a = 0; a < AA; ++a)
      bti[(size_t)b * PP + ovp[a]] = (unsigned char)(a | 32);
  }
}

// ---------------------------------------------------------------------------
// K2: conf loss for all priors (writes lossm + radix hist pass 1), sparse
// loc / landmark losses for positives. Per-batch double accumulators.
// ---------------------------------------------------------------------------
__global__ __launch_bounds__(256) void k_loss(
    const float* __restrict__ loc, const float* __restrict__ conf,
    const float* __restrict__ loc5, const float* __restrict__ priors,
    const float* __restrict__ targets,
    const unsigned char* __restrict__ bti, float* __restrict__ lossm,
    unsigned* __restrict__ H1,
    double* __restrict__ accL, double* __restrict__ accC,
    double* __restrict__ accLM, int* __restrict__ numpos) {
#pragma clang fp contract(off)
  const int b = blockIdx.y;
  const int tid = threadIdx.x;
  __shared__ float tr[AA][15];
  __shared__ unsigned h[2048];
  for (int i = tid; i < 2048; i += 256) h[i] = 0;
  if (tid < AA) {
    const float* tg = targets + ((size_t)b * AA + tid) * 15;
#pragma unroll
    for (int j = 0; j < 15; ++j) tr[tid][j] = tg[j];
  }
  __syncthreads();

  double ll = 0.0, lc = 0.0, lm = 0.0;
  int np = 0;
  const int base = blockIdx.x * 2048;
  for (int it = 0; it < 8; ++it) {
    const int p = base + it * 256 + tid;
    const size_t gp = (size_t)b * PP + p;
    const unsigned char f = bti[gp];
    const int idx = f & 31;
    const bool posf = (f & 32) != 0;
    const int cls = posf ? (int)tr[idx][4] : 0;
    const bool pos = cls > 0;

    const float2 cc = reinterpret_cast<const float2*>(conf)[gp];
    const float mx = fmaxf(cc.x, cc.y);
    const float lse = mx + logf(expf(cc.x - mx) + expf(cc.y - mx));
    const float gtl = (cls >= 1) ? cc.y : cc.x;
    const float lca = lse - gtl;
    const float v = pos ? 0.f : lca;
    lossm[gp] = v;
    atomicAdd(&h[__float_as_uint(v) >> 21], 1u);  // radix pass 1 (bits 31:21)

    if (pos) {
      ++np;
      lc += (double)lca;
      const float4 pr = reinterpret_cast<const float4*>(priors)[p];
      const float m0 = tr[idx][0], m1 = tr[idx][1];
      const float m2 = tr[idx][2], m3 = tr[idx][3];
      const float vx = 0.1f * pr.z, vy = 0.1f * pr.w;
      const float t0 = ((m0 + m2) / 2.0f - pr.x) / vx;
      const float t1 = ((m1 + m3) / 2.0f - pr.y) / vy;
      const float t2 = logf((m2 - m0) / pr.z) / 0.2f;
      const float t3 = logf((m3 - m1) / pr.w) / 0.2f;
      const float* lp = loc + gp * 4;
      float s = 0.f;
      {
        float d = lp[0] - t0, ad = fabsf(d);
        s += (ad < 1.f) ? 0.5f * d * d : ad - 0.5f;
        d = lp[1] - t1; ad = fabsf(d);
        s += (ad < 1.f) ? 0.5f * d * d : ad - 0.5f;
        d = lp[2] - t2; ad = fabsf(d);
        s += (ad < 1.f) ? 0.5f * d * d : ad - 0.5f;
        d = lp[3] - t3; ad = fabsf(d);
        s += (ad < 1.f) ? 0.5f * d * d : ad - 0.5f;
      }
      ll += (double)s;
      const float* l5 = loc5 + gp * 10;
      float s2 = 0.f;
#pragma unroll
      for (int j = 0; j < 5; ++j) {
        const float tx = (tr[idx][5 + 2 * j] - pr.x) / vx;
        const float ty = (tr[idx][6 + 2 * j] - pr.y) / vy;
        const float dx = l5[2 * j] - tx;
        const float dy = l5[2 * j + 1] - ty;
        s2 += dx * dx + dy * dy;
      }
      lm += (double)s2;
    }
  }
#pragma unroll
  for (int off = 1; off < 64; off <<= 1) {
    ll += __shfl_xor(ll, off, 64);
    lc += __shfl_xor(lc, off, 64);
    lm += __shfl_xor(lm, off, 64);
    np += __shfl_xor(np, off, 64);
  }
  __shared__ double rl[4], rc[4], rm[4];
  __shared__ int rn[4];
  const int wave = tid >> 6, lane = tid & 63;
  if (lane == 0) { rl[wave] = ll; rc[wave] = lc; rm[wave] = lm; rn[wave] = np; }
  __syncthreads();
  if (tid == 0) {
    atomicAdd(&accL[b], rl[0] + rl[1] + rl[2] + rl[3]);
    atomicAdd(&accC[b], rc[0] + rc[1] + rc[2] + rc[3]);
    atomicAdd(&accLM[b], rm[0] + rm[1] + rm[2] + rm[3]);
    atomicAdd(&numpos[b], rn[0] + rn[1] + rn[2] + rn[3]);
  }
  // flush pass-1 histogram (sparse)
  unsigned* Hb = H1 + b * 2048;
  for (int i = tid; i < 2048; i += 256) {
    const unsigned c = h[i];
    if (c) atomicAdd(&Hb[i], c);
  }
}

// ---------------------------------------------------------------------------
// In-block redundant select over an LDS-loaded histogram (descending bins).
// All threads participate; result broadcast via s_out[0]=bin, s_out[1]=krem'.
// ---------------------------------------------------------------------------
template <int NBINS>
__device__ __forceinline__ void selscan(const unsigned* __restrict__ H,
                                        unsigned krem_in, unsigned* s_out,
                                        unsigned* hb, unsigned* csum,
                                        int tid) {
  constexpr int CH = NBINS / 256;
  for (int i = tid; i < NBINS; i += 256) hb[i] = H[i];
  __syncthreads();
  const int start = NBINS - 1 - tid * CH;
  unsigned msum = 0;
#pragma unroll
  for (int j = 0; j < CH; ++j) msum += hb[start - j];
  csum[tid] = msum;
  __syncthreads();
  if (tid == 0) {
    unsigned cum = 0;
    int c = 0;
    while (c < 255 && cum + csum[c] < krem_in) { cum += csum[c]; ++c; }
    const int st = NBINS - 1 - c * CH;
    int bin = st - (CH - 1);
    for (int j = 0; j < CH; ++j) {
      const unsigned hh = hb[st - j];
      if (cum + hh >= krem_in) { bin = st - j; break; }
      cum += hh;
    }
    s_out[0] = (unsigned)bin;
    s_out[1] = krem_in - cum;
  }
  __syncthreads();
}

// ---------------------------------------------------------------------------
// K3: redundant select-1 from H1 (block (0,b) publishes sel1), then radix
// hist pass 2 (bits 20:10) into H2. Grid (8, BB) x 256.
// ---------------------------------------------------------------------------
__global__ __launch_bounds__(256) void k_hist2sel(
    const float* __restrict__ lossm, const unsigned* __restrict__ H1,
    unsigned* __restrict__ H2, const int* __restrict__ numpos,
    unsigned* __restrict__ sel1) {
  const int b = blockIdx.y;
  const int tid = threadIdx.x;
  __shared__ unsigned hb[2048], csum[256], sout[2], h[2048];
  long long K = 7LL * (long long)numpos[b];
  if (K > PP - 1) K = PP - 1;
  if (K < 0) K = 0;
  selscan<2048>(H1 + b * 2048, (unsigned)K, sout, hb, csum, tid);
  const unsigned bin1 = sout[0], krem1 = sout[1];
  if (blockIdx.x == 0 && tid == 0) { sel1[b * 2] = bin1; sel1[b * 2 + 1] = krem1; }
  for (int i = tid; i < 2048; i += 256) h[i] = 0;
  __syncthreads();
  const float4* v4 = reinterpret_cast<const float4*>(lossm + (size_t)b * PP) +
                     (size_t)blockIdx.x * 4096;
#pragma unroll 4
  for (int k = 0; k < 16; ++k) {
    const float4 x = v4[tid + k * 256];
    const unsigned u0 = __float_as_uint(x.x), u1 = __float_as_uint(x.y);
    const unsigned u2 = __float_as_uint(x.z), u3 = __float_as_uint(x.w);
    if ((u0 >> 21) == bin1) atomicAdd(&h[(u0 >> 10) & 2047], 1u);
    if ((u1 >> 21) == bin1) atomicAdd(&h[(u1 >> 10) & 2047], 1u);
    if ((u2 >> 21) == bin1) atomicAdd(&h[(u2 >> 10) & 2047], 1u);
    if ((u3 >> 21) == bin1) atomicAdd(&h[(u3 >> 10) & 2047], 1u);
  }
  __syncthreads();
  unsigned* Hb = H2 + b * 2048;
  for (int i = tid; i < 2048; i += 256) {
    const unsigned c = h[i];
    if (c) atomicAdd(&Hb[i], c);
  }
}

// ---------------------------------------------------------------------------
// K4: redundant select-2 from H2, then pass 3 (bits 9:0) into H3.
// ---------------------------------------------------------------------------
__global__ __launch_bounds__(256) void k_hist3sel(
    const float* __restrict__ lossm, const unsigned* __restrict__ H2,
    unsigned* __restrict__ H3, const unsigned* __restrict__ sel1,
    unsigned* __restrict__ sel2) {
  const int b = blockIdx.y;
  const int tid = threadIdx.x;
  __shared__ unsigned hb[2048], csum[256], sout[2], h[1024];
  const unsigned bin1 = sel1[b * 2], krem1 = sel1[b * 2 + 1];
  selscan<2048>(H2 + b * 2048, krem1, sout, hb, csum, tid);
  const unsigned bin2 = sout[0], krem2 = sout[1];
  if (blockIdx.x == 0 && tid == 0) { sel2[b * 2] = bin2; sel2[b * 2 + 1] = krem2; }
  for (int i = tid; i < 1024; i += 256) h[i] = 0;
  __syncthreads();
  const float4* v4 = reinterpret_cast<const float4*>(lossm + (size_t)b * PP) +
                     (size_t)blockIdx.x * 4096;
#pragma unroll 4
  for (int k = 0; k < 16; ++k) {
    const float4 x = v4[tid + k * 256];
    const unsigned u0 = __float_as_uint(x.x), u1 = __float_as_uint(x.y);
    const unsigned u2 = __float_as_uint(x.z), u3 = __float_as_uint(x.w);
    if ((u0 >> 21) == bin1 && ((u0 >> 10) & 2047) == bin2)
      atomicAdd(&h[u0 & 1023], 1u);
    if ((u1 >> 21) == bin1 && ((u1 >> 10) & 2047) == bin2)
      atomicAdd(&h[u1 & 1023], 1u);
    if ((u2 >> 21) == bin1 && ((u2 >> 10) & 2047) == bin2)
      atomicAdd(&h[u2 & 1023], 1u);
    if ((u3 >> 21) == bin1 && ((u3 >> 10) & 2047) == bin2)
      atomicAdd(&h[u3 & 1023], 1u);
  }
  __syncthreads();
  unsigned* Hb = H3 + b * 2048;
  for (int i = tid; i < 1024; i += 256) {
    const unsigned c = h[i];
    if (c) atomicAdd(&Hb[i], c);
  }
}

// ---------------------------------------------------------------------------
// K5: redundant select-3 from H3 -> exact threshold; sum lossm strictly
// above it; block (0,b) publishes sel3 = {thr_bits, krem} for k_final.
// ---------------------------------------------------------------------------
__global__ __launch_bounds__(256) void k_sumtop2(
    const float* __restrict__ lossm, const unsigned* __restrict__ H3,
    const unsigned* __restrict__ sel1, const unsigned* __restrict__ sel2,
    unsigned* __restrict__ sel3, double* __restrict__ accC) {
  const int b = blockIdx.y;
  const int tid = threadIdx.x;
  __shared__ unsigned hb[1024], csum[256], sout[2];
  const unsigned bin1 = sel1[b * 2];
  const unsigned bin2 = sel2[b * 2], krem2 = sel2[b * 2 + 1];
  selscan<1024>(H3 + b * 2048, krem2, sout, hb, csum, tid);
  const unsigned bin3 = sout[0], krem3 = sout[1];
  const unsigned pref = (bin1 << 21) | (bin2 << 10) | bin3;
  if (blockIdx.x == 0 && tid == 0) { sel3[b * 2] = pref; sel3[b * 2 + 1] = krem3; }
  const float4* v4 = reinterpret_cast<const float4*>(lossm + (size_t)b * PP) +
                     (size_t)blockIdx.x * 4096;
  double s = 0.0;
#pragma unroll 4
  for (int k = 0; k < 16; ++k) {
    const float4 x = v4[tid + k * 256];
    if (__float_as_uint(x.x) > pref) s += (double)x.x;
    if (__float_as_uint(x.y) > pref) s += (double)x.y;
    if (__float_as_uint(x.z) > pref) s += (double)x.z;
    if (__float_as_uint(x.w) > pref) s += (double)x.w;
  }
#pragma unroll
  for (int off = 1; off < 64; off <<= 1) s += __shfl_xor(s, off, 64);
  __shared__ double rs[4];
  const int wave = tid >> 6, lane = tid & 63;
  if (lane == 0) rs[wave] = s;
  __syncthreads();
  if (tid == 0) atomicAdd(&accC[b], rs[0] + rs[1] + rs[2] + rs[3]);
}

// ---------------------------------------------------------------------------
// K6: finalize -> d_out[3]; adds krem*thr tie contribution per batch.
// ---------------------------------------------------------------------------
__global__ void k_final(const double* __restrict__ accL,
                        const double* __restrict__ accC,
                        const double* __restrict__ accLM,
                        const int* __restrict__ numpos,
                        const unsigned* __restrict__ sel3,
                        float* __restrict__ out) {
  if (threadIdx.x == 0 && blockIdx.x == 0) {
    long long tot = 0;
    double sl = 0, sc = 0, sm = 0;
    for (int b = 0; b < BB; ++b) {
      tot += numpos[b];
      sl += accL[b];
      sc += accC[b];
      const unsigned krem = sel3[b * 2 + 1];
      if (krem > 0)
        sc += (double)krem * (double)__uint_as_float(sel3[b * 2]);
      sm += accLM[b];
    }
    float N = (float)tot;
    if (N < 1.f) N = 1.f;
    out[0] = (float)(sl / (double)N);
    out[1] = (float)(sc / (double)N);
    out[2] = (float)(sm / (double)N);
  }
}

extern "C" void kernel_launch(void* const* d_in, const int* in_sizes, int n_in,
                              void* d_out, int out_size, void* d_ws,
                              size_t ws_size, hipStream_t stream) {
  const float* loc = (const float*)d_in[0];
  const float* conf = (const float*)d_in[1];
  const float* loc5 = (const float*)d_in[2];
  const float* priors = (const float*)d_in[3];
  const float* tgt = (const float*)d_in[4];
  char* ws = (char*)d_ws;
  double* accL = (double*)(ws + OFF_ACCL);
  double* accC = (double*)(ws + OFF_ACCC);
  double* accLM = (double*)(ws + OFF_ACCLM);
  int* numpos = (int*)(ws + OFF_NP);
  unsigned* sel1 = (unsigned*)(ws + OFF_SEL1);
  unsigned* sel2 = (unsigned*)(ws + OFF_SEL2);
  unsigned* sel3 = (unsigned*)(ws + OFF_SEL3);
  unsigned long long* gpart = (unsigned long long*)(ws + OFF_GPART);
  unsigned* H1 = (unsigned*)(ws + OFF_H1);
  unsigned* H2 = (unsigned*)(ws + OFF_H2);
  unsigned* H3 = (unsigned*)(ws + OFF_H3);
  unsigned char* bti = (unsigned char*)(ws + OFF_BTI);
  float* lossm = (float*)(ws + OFF_LM);

  // zero accumulators/numpos/sel (2 KiB) and the three histograms (768 KiB)
  hipMemsetAsync(ws, 0, 2048, stream);
  hipMemsetAsync(ws + OFF_H1, 0, (size_t)3 * BB * 2048 * 4, stream);

  dim3 grid(PP / 2048, BB);
  k_match2<<<grid, 256, 0, stream>>>(priors, tgt, bti, gpart);
  k_truthapply<<<BB, 256, 0, stream>>>(gpart, bti);
  k_loss<<<grid, 256, 0, stream>>>(loc, conf, loc5, priors, tgt, bti, lossm,
                                   H1, accL, accC, accLM, numpos);
  dim3 hgrid(8, BB);
  k_hist2sel<<<hgrid, 256, 0, stream>>>(lossm, H1, H2, numpos, sel1);
  k_hist3sel<<<hgrid, 256, 0, stream>>>(lossm, H2, H3, sel1, sel2);
  k_sumtop2<<<hgrid, 256, 0, stream>>>(lossm, H3, sel1, sel2, sel3, accC);
  k_final<<<1, 64, 0, stream>>>(accL, accC, accLM, numpos, sel3,
                                (float*)d_out);
}